// Round 8
// baseline (222.266 us; speedup 1.0000x reference)
//
#include <hip/hip_runtime.h>

// ROI Align (FPN, PH=PW=7, SR=2), fp32 I/O.
// R17 = R16 RESUBMIT (container acquisition failed twice; no compile or
// correctness signal. Bounds/LDS/workspace audit found no fault path —
// same flake signature as R12, which passed unchanged on resubmit).
// R16: full channel-last conversion, divergent path eliminated (when ws fits).
// Calibrated model (R9-R15): cost ~= line-touches x {4.4cy divergent, 2.6cy
// contiguous} (~L2 line service). l0 divergent gather is floored at ~35-45us
// (no intra-roi line redundancy); converting l0 to channel-last costs 164MB
// of pure BW (~26us) and drops its gather to ~4us contiguous.
// Pipeline (full-ws path):
//   L1 k_t13  : transpose l1-3 -> ws        (54MB,  ~9us, BW-bound)
//   L2 k_t0g13: transpose l0 (x4-vectorized, 164MB, ~26us) OVERLAPPED with
//               gather of all l1-3 rois (reads only l1-3 tables, ~15us)
//   L3 k_g0   : gather l0 rois from t0      (~5-8us, contiguous)
// Fallbacks: ws >= 26.9MB -> R15 split with gather-FIRST ordering (fixes the
// 13us serialization); tiny ws -> R11 all-divergent.
// Predicted: t13 8-13us; t0g13 26-34us @ 4-6TB/s; g0 4-8us; total 40-55us.

#define NUM_CH 256
#define CGRP   64
#define OFF_T2 5120000      // floats: t1 = 2*100*100*256
#define OFF_T3 6400000      // + 2*50*50*256
#define WS_SMALL 6720000    // + 2*25*25*256 (l1-3 tables)
#define OFF_T0 6720000      // t0 starts here
#define WS_FULL 27200000    // + 2*200*200*256
#define TBLK13 1400         // 800 (l1) + 400 (l2) + 200 (l3)
#define TBLK0  3200         // 2 * 200 rows * 4 ctiles * 2 xhalves

typedef float floatx2 __attribute__((ext_vector_type(2)));
typedef float floatx4 __attribute__((ext_vector_type(4)));

__device__ __forceinline__ float ext4(floatx4 v, int i) {
    float r = (i == 1) ? v.y : v.x;
    r = (i == 2) ? v.z : r;
    r = (i == 3) ? v.w : r;
    return r;
}

// ---- transpose one (b, y, ctile-of-64) row: (C,H,W) -> (H,W,C) (proven) ---
template<int H, int W, int P>
__device__ __forceinline__ void transpose_row(
    const float* __restrict__ src, float* __restrict__ dst, int m, float* lds)
{
    int b  = m / (H * 4);
    int rm = m - b * (H * 4);
    int y  = rm >> 2;
    int ct = rm & 3;
    int tid = threadIdx.x;
    const float* s = src + (((size_t)b * NUM_CH + ct * 64) * H + y) * W;
    for (int i = tid; i < 64 * W; i += 256) {
        int c = i / W;
        int x = i - c * W;
        lds[c * P + x] = s[(size_t)c * (H * W) + x];
    }
    __syncthreads();
    float* d = dst + (((size_t)b * H + y) * (size_t)W) * NUM_CH + ct * 64;
    for (int i = tid; i < W * 64; i += 256) {
        int x = i >> 6;
        int c = i & 63;
        d[(size_t)x * NUM_CH + c] = lds[c * P + x];
    }
}

// ---- l0 transpose, x4-vectorized both sides. m in [0,3200) ----------------
__device__ __forceinline__ void transpose_l0(
    const float* __restrict__ src, float* __restrict__ dst, int m, float* lds)
{
    int b   = m / 1600;
    int rm  = m - b * 1600;
    int y   = rm >> 3;
    int sub = rm & 7;
    int ct  = sub >> 1;
    int xh  = sub & 1;
    int tid = threadIdx.x;
    const float* s = src + (((size_t)b * NUM_CH + ct * 64) * 200 + y) * 200
                         + xh * 100;
    for (int i = tid; i < 64 * 25; i += 256) {      // 64 ch x 25 dwordx4
        int c  = i / 25;
        int xq = i - c * 25;
        floatx4 v = *(const floatx4*)(s + (size_t)c * 40000 + xq * 4);
        float* L = lds + c * 101 + xq * 4;
        L[0] = v.x; L[1] = v.y; L[2] = v.z; L[3] = v.w;
    }
    __syncthreads();
    float* d = dst + (((size_t)b * 200 + y) * 200 + xh * 100) * (size_t)NUM_CH
                   + ct * 64;
    for (int i = tid; i < 100 * 16; i += 256) {     // 100 px x 16 dwordx4
        int x  = i >> 4;
        int cq = (i & 15) * 4;
        floatx4 v;
        v.x = lds[(cq + 0) * 101 + x];
        v.y = lds[(cq + 1) * 101 + x];
        v.z = lds[(cq + 2) * 101 + x];
        v.w = lds[(cq + 3) * 101 + x];
        *(floatx4*)(d + (size_t)x * NUM_CH + cq) = v;
    }
}

// ---- coalesced channel-last gather of one roi (proven R15 k2 body) --------
__device__ __forceinline__ void gather_roi(
    const float* __restrict__ t, int H, int W, float scale,
    const float* __restrict__ rf, float* __restrict__ outk, float* lds)
{
    float r0 = rf[0];
    float x1 = rf[1] * scale, y1 = rf[2] * scale;
    float x2 = rf[3] * scale, y2 = rf[4] * scale;
    int bi = (int)r0;
    bi = (bi < 0) ? 0 : ((bi > 1) ? 1 : bi);

    float bh = fmaxf(y2 - y1, 1.0f) * (1.0f / 7.0f);
    float bw = fmaxf(x2 - x1, 1.0f) * (1.0f / 7.0f);

    const float* tb = t + (size_t)bi * H * W * NUM_CH;
    int wave = threadIdx.x >> 6;
    int lane = threadIdx.x & 63;
    int cb   = lane * 4;

    for (int px = wave; px < 49; px += 4) {
        int ph = px / 7, pw = px % 7;

        int rows[4]; float lyv[2], hyv[2], vy[2];
        #pragma unroll
        for (int sy = 0; sy < 2; ++sy) {
            float y = y1 + (float)ph * bh + ((float)sy + 0.5f) * (bh * 0.5f);
            bool valid = (y > -1.0f) && (y < (float)H);
            float yc = fmaxf(y, 0.0f);
            int yl = min((int)yc, H - 1);
            int yh = min(yl + 1, H - 1);
            float ly = (yl >= H - 1) ? 0.0f : (yc - (float)yl);
            rows[2 * sy]     = yl;
            rows[2 * sy + 1] = yh;
            lyv[sy] = ly; hyv[sy] = 1.0f - ly;
            vy[sy] = valid ? 0.25f : 0.0f;
        }
        int cols[4]; float lxv[2], hxv[2], vx[2];
        #pragma unroll
        for (int sx = 0; sx < 2; ++sx) {
            float x = x1 + (float)pw * bw + ((float)sx + 0.5f) * (bw * 0.5f);
            bool valid = (x > -1.0f) && (x < (float)W);
            float xc = fmaxf(x, 0.0f);
            int xl = min((int)xc, W - 1);
            float lx = (xl >= W - 1) ? 0.0f : (xc - (float)xl);
            cols[2 * sx]     = xl;
            cols[2 * sx + 1] = min(xl + 1, W - 1);
            lxv[sx] = lx; hxv[sx] = 1.0f - lx;
            vx[sx] = valid ? 1.0f : 0.0f;
        }

        floatx4 v[4][4];
        #pragma unroll
        for (int rr = 0; rr < 4; ++rr) {
            #pragma unroll
            for (int cc = 0; cc < 4; ++cc) {
                v[rr][cc] = *(const floatx4*)(
                    tb + ((size_t)rows[rr] * W + cols[cc]) * NUM_CH + cb);
            }
        }

        floatx4 acc = {0.0f, 0.0f, 0.0f, 0.0f};
        #pragma unroll
        for (int sy = 0; sy < 2; ++sy) {
            #pragma unroll
            for (int sx = 0; sx < 2; ++sx) {
                float vs  = vy[sy] * vx[sx];
                float w00 = hyv[sy] * hxv[sx] * vs;
                float w01 = hyv[sy] * lxv[sx] * vs;
                float w10 = lyv[sy] * hxv[sx] * vs;
                float w11 = lyv[sy] * lxv[sx] * vs;
                acc += v[2 * sy][2 * sx]         * w00;
                acc += v[2 * sy][2 * sx + 1]     * w01;
                acc += v[2 * sy + 1][2 * sx]     * w10;
                acc += v[2 * sy + 1][2 * sx + 1] * w11;
            }
        }

        int lb = px * 257 + cb;
        lds[lb + 0] = acc.x;
        lds[lb + 1] = acc.y;
        lds[lb + 2] = acc.z;
        lds[lb + 3] = acc.w;
    }
    __syncthreads();

    for (int i = threadIdx.x; i < NUM_CH * 49; i += 256) {
        int c  = i / 49;
        int px = i - c * 49;
        outk[i] = lds[px * 257 + c];
    }
}

// ==== L1: transpose l1,l2,l3 ==============================================
__global__ __launch_bounds__(256) void k_t13(
    const float* __restrict__ f1, const float* __restrict__ f2,
    const float* __restrict__ f3, float* __restrict__ ws)
{
    __shared__ float lds[64 * 101];
    int bid = blockIdx.x;
    if (bid < 800)       transpose_row<100, 100, 101>(f1, ws,          bid,        lds);
    else if (bid < 1200) transpose_row<50,  50,  51 >(f2, ws + OFF_T2, bid - 800,  lds);
    else                 transpose_row<25,  25,  27 >(f3, ws + OFF_T3, bid - 1200, lds);
}

// ==== L2: transpose l0 (bulk) || gather all l1-3 rois ======================
__global__ __launch_bounds__(256) void k_t0g13(
    const float* __restrict__ f0,
    const float* __restrict__ rois_f,
    const int* __restrict__ level,
    float* __restrict__ ws,
    float* __restrict__ out,
    int K)
{
    __shared__ float lds[49 * 257];                 // 50.4KB; t0 uses 6.4K
    int bid = blockIdx.x;
    if (bid < K) {
        int k = bid;
        int lvl = level[k];
        if (lvl == 0) return;                       // k_g0 owns level 0
        const float* t; int H, W; float scale;
        if (lvl == 1)      { t = ws;          H = 100; W = 100; scale = 0.125f;   }
        else if (lvl == 2) { t = ws + OFF_T2; H = 50;  W = 50;  scale = 0.0625f;  }
        else               { t = ws + OFF_T3; H = 25;  W = 25;  scale = 0.03125f; }
        gather_roi(t, H, W, scale, rois_f + (size_t)k * 5,
                   out + (size_t)k * (NUM_CH * 49), lds);
    } else {
        transpose_l0(f0, ws + OFF_T0, bid - K, lds);
    }
}

// ==== L3: gather l0 rois ===================================================
__global__ __launch_bounds__(256) void k_g0(
    const float* __restrict__ rois_f,
    const int* __restrict__ level,
    const float* __restrict__ ws,
    float* __restrict__ out,
    int K)
{
    __shared__ float lds[49 * 257];
    int k = blockIdx.x;
    if (level[k] != 0) return;
    gather_roi(ws + OFF_T0, 200, 200, 0.25f, rois_f + (size_t)k * 5,
               out + (size_t)k * (NUM_CH * 49), lds);
}

// ==== Fallback: R15 k1 with gather-FIRST ordering ==========================
__global__ __launch_bounds__(256) void k1_fallback(
    const float* __restrict__ f0, const float* __restrict__ f1,
    const float* __restrict__ f2, const float* __restrict__ f3,
    const float* __restrict__ rois_f, const int* __restrict__ level,
    float* __restrict__ out, float* __restrict__ ws,
    int K, int GB, int TBLK, int all_levels)
{
    __shared__ float lds[64 * 101];
    int bid = blockIdx.x;
    if (bid >= GB) {
        int m = bid - GB;
        if (m < 800)       transpose_row<100, 100, 101>(f1, ws,          m,        lds);
        else if (m < 1200) transpose_row<50,  50,  51 >(f2, ws + OFF_T2, m - 800,  lds);
        else               transpose_row<25,  25,  27 >(f3, ws + OFF_T3, m - 1200, lds);
        return;
    }

    int nb  = GB;
    int q   = nb >> 3, r = nb & 7;
    int xcd = bid & 7;
    int idx = bid >> 3;
    int l   = xcd * q + min(xcd, r) + idx;

    int NW  = K * CGRP;
    int wid = l * 4 + (int)(threadIdx.x >> 6);
    if (wid >= NW) return;
    int lane = threadIdx.x & 63;
    if (lane >= 49) return;

    int k  = wid % K;
    int c2 = wid / K;
    k  = __builtin_amdgcn_readfirstlane(k);
    c2 = __builtin_amdgcn_readfirstlane(c2);

    int lvl = level[k];
    if (!all_levels && lvl != 0) return;

    const float* f;
    int H, W; float scale;
    if (lvl == 0)      { f = f0; H = 200; W = 200; scale = 0.25f;    }
    else if (lvl == 1) { f = f1; H = 100; W = 100; scale = 0.125f;   }
    else if (lvl == 2) { f = f2; H = 50;  W = 50;  scale = 0.0625f;  }
    else               { f = f3; H = 25;  W = 25;  scale = 0.03125f; }

    int p  = lane;
    int ph = p / 7;
    int pw = p % 7;

    const float* rf = rois_f + (size_t)k * 5;
    float r0 = rf[0];
    float x1 = rf[1] * scale, y1 = rf[2] * scale;
    float x2 = rf[3] * scale, y2 = rf[4] * scale;
    int bi = (int)r0;
    bi = (bi < 0) ? 0 : ((bi > 1) ? 1 : bi);

    float bh = fmaxf(y2 - y1, 1.0f) * (1.0f / 7.0f);
    float bw = fmaxf(x2 - x1, 1.0f) * (1.0f / 7.0f);

    const size_t plane = (size_t)(H * W);
    const float* base  = f + ((size_t)bi * NUM_CH + c2) * plane;
    const size_t cstr  = (size_t)CGRP * plane;

    int   rA[2], rB[2];
    float lyv[2], hyv[2], vy[2];
    #pragma unroll
    for (int sy = 0; sy < 2; ++sy) {
        float y = y1 + (float)ph * bh + ((float)sy + 0.5f) * (bh * 0.5f);
        bool valid = (y > -1.0f) && (y < (float)H);
        float yc = fmaxf(y, 0.0f);
        int yl = min((int)yc, H - 1);
        int yh = min(yl + 1, H - 1);
        float ly = (yl >= H - 1) ? 0.0f : (yc - (float)yl);
        rA[sy] = yl * W;
        rB[sy] = yh * W;
        lyv[sy] = ly; hyv[sy] = 1.0f - ly;
        vy[sy] = valid ? 0.25f : 0.0f;
    }
    int   xlv[2], xhv[2];
    float lxv[2], hxv[2], vx[2];
    #pragma unroll
    for (int sx = 0; sx < 2; ++sx) {
        float x = x1 + (float)pw * bw + ((float)sx + 0.5f) * (bw * 0.5f);
        bool valid = (x > -1.0f) && (x < (float)W);
        float xc = fmaxf(x, 0.0f);
        int xl = min((int)xc, W - 1);
        float lx = (xl >= W - 1) ? 0.0f : (xc - (float)xl);
        xlv[sx] = xl;
        xhv[sx] = min(xl + 1, W - 1);
        lxv[sx] = lx; hxv[sx] = 1.0f - lx;
        vx[sx] = valid ? 1.0f : 0.0f;
    }

    float acc[4];
    #pragma unroll
    for (int j = 0; j < 4; ++j) acc[j] = 0.0f;

    if (bw <= 3.98f) {
        int xq = min(xlv[0], W - 4);
        int i0l = min(max(xlv[0] - xq, 0), 3);
        int i0h = min(max(xhv[0] - xq, 0), 3);
        int i1l = min(max(xlv[1] - xq, 0), 3);
        int i1h = min(max(xhv[1] - xq, 0), 3);

        #pragma unroll
        for (int sy = 0; sy < 2; ++sy) {
            floatx4 LA[4], LB[4];
            #pragma unroll
            for (int j = 0; j < 4; ++j) {
                const float* bj = base + (size_t)j * cstr;
                LA[j] = *(const floatx4*)(bj + rA[sy] + xq);
                LB[j] = *(const floatx4*)(bj + rB[sy] + xq);
            }
            #pragma unroll
            for (int sx = 0; sx < 2; ++sx) {
                int il = sx ? i1l : i0l;
                int ih = sx ? i1h : i0h;
                float vs  = vy[sy] * vx[sx];
                float w00 = hyv[sy] * hxv[sx] * vs;
                float w01 = hyv[sy] * lxv[sx] * vs;
                float w10 = lyv[sy] * hxv[sx] * vs;
                float w11 = lyv[sy] * lxv[sx] * vs;
                #pragma unroll
                for (int j = 0; j < 4; ++j) {
                    acc[j] += w00 * ext4(LA[j], il) + w01 * ext4(LA[j], ih)
                            + w10 * ext4(LB[j], il) + w11 * ext4(LB[j], ih);
                }
            }
        }
    } else {
        int   xb[2];
        float sel[2];
        #pragma unroll
        for (int sx = 0; sx < 2; ++sx) {
            int xq = min(xlv[sx], W - 2);
            xb[sx]  = xq;
            sel[sx] = (xlv[sx] > xq) ? 1.0f : 0.0f;
        }
        #pragma unroll
        for (int sy = 0; sy < 2; ++sy) {
            floatx2 va[4][2], vb[4][2];
            #pragma unroll
            for (int sx = 0; sx < 2; ++sx) {
                #pragma unroll
                for (int j = 0; j < 4; ++j) {
                    const float* bj = base + (size_t)j * cstr;
                    va[j][sx] = *(const floatx2*)(bj + rA[sy] + xb[sx]);
                    vb[j][sx] = *(const floatx2*)(bj + rB[sy] + xb[sx]);
                }
            }
            #pragma unroll
            for (int sx = 0; sx < 2; ++sx) {
                float vs  = vy[sy] * vx[sx];
                float w00 = hyv[sy] * hxv[sx] * vs;
                float w01 = hyv[sy] * lxv[sx] * vs;
                float w10 = lyv[sy] * hxv[sx] * vs;
                float w11 = lyv[sy] * lxv[sx] * vs;
                float s0  = sel[sx];
                #pragma unroll
                for (int j = 0; j < 4; ++j) {
                    float v00 = va[j][sx].x + s0 * (va[j][sx].y - va[j][sx].x);
                    float v10 = vb[j][sx].x + s0 * (vb[j][sx].y - vb[j][sx].x);
                    acc[j] += w00 * v00 + w01 * va[j][sx].y
                            + w10 * v10 + w11 * vb[j][sx].y;
                }
            }
        }
    }

    size_t ob = ((size_t)k * NUM_CH + c2) * 49 + p;
    #pragma unroll
    for (int j = 0; j < 4; ++j)
        out[ob + (size_t)j * (CGRP * 49)] = acc[j];
}

__global__ __launch_bounds__(256) void k2_fallback(
    const float* __restrict__ rois_f,
    const int* __restrict__ level,
    const float* __restrict__ ws,
    float* __restrict__ out,
    int K)
{
    __shared__ float lds[49 * 257];
    int k = blockIdx.x;
    int lvl = level[k];
    if (lvl == 0) return;
    const float* t; int H, W; float scale;
    if (lvl == 1)      { t = ws;          H = 100; W = 100; scale = 0.125f;   }
    else if (lvl == 2) { t = ws + OFF_T2; H = 50;  W = 50;  scale = 0.0625f;  }
    else               { t = ws + OFF_T3; H = 25;  W = 25;  scale = 0.03125f; }
    gather_roi(t, H, W, scale, rois_f + (size_t)k * 5,
               out + (size_t)k * (NUM_CH * 49), lds);
}

extern "C" void kernel_launch(void* const* d_in, const int* in_sizes, int n_in,
                              void* d_out, int out_size, void* d_ws, size_t ws_size,
                              hipStream_t stream) {
    const float* f0   = (const float*)d_in[0];
    const float* f1   = (const float*)d_in[1];
    const float* f2   = (const float*)d_in[2];
    const float* f3   = (const float*)d_in[3];
    const float* rois = (const float*)d_in[4];
    // d_in[5] = rois_counts (unused)
    const int* level = (const int*)d_in[6];
    float* out = (float*)d_out;
    float* ws  = (float*)d_ws;

    int K = out_size / (NUM_CH * 49);

    if (ws_size >= (size_t)WS_FULL * 4) {
        k_t13<<<TBLK13, 256, 0, stream>>>(f1, f2, f3, ws);
        k_t0g13<<<K + TBLK0, 256, 0, stream>>>(f0, rois, level, ws, out, K);
        k_g0<<<K, 256, 0, stream>>>(rois, level, ws, out, K);
    } else if (ws_size >= (size_t)WS_SMALL * 4) {
        int GB = K * 16;
        k1_fallback<<<GB + TBLK13, 256, 0, stream>>>(
            f0, f1, f2, f3, rois, level, out, ws, K, GB, TBLK13, 0);
        k2_fallback<<<K, 256, 0, stream>>>(rois, level, ws, out, K);
    } else {
        int GB = K * 16;
        k1_fallback<<<GB, 256, 0, stream>>>(
            f0, f1, f2, f3, rois, level, out, ws, K, GB, 0, 1);
    }
}

// Round 9
// 208.612 us; speedup vs baseline: 1.0655x; 1.0655x over previous
//
#include <hip/hip_runtime.h>

// ROI Align (FPN, PH=PW=7, SR=2), fp32 I/O.
// R18: transpose ONLY l0 (the level whose divergent gather is expensive),
// overlapped in one kernel with the LDS-FREE R11 divergent gather of l1-3.
// Post-mortem R17: k_t0g13 ran at 2.56TB/s / 25% occupancy because
// gather_roi's 50.4KB LDS tile was charged to every transpose block
// (3 blocks/CU). Also transposing l1-3 cost ~13us (k_t13) to save ~12us of
// already-cheap l1-3 divergent gather. Both reverted.
// Model (R9-R17): divergent gather = line-events x ~4.4cy/CU; contiguous =
// ~2.6cy/line (BW). l0-divergent ~43us, l1-3-divergent ~26us (R15 decomp).
//   kM : 3200 l0-transpose blocks (164MB BW) FIRST + R11 gather l1-3
//        (no LDS) -> kernel LDS 25.9KB -> 6 blocks/CU. Overlap BW+latency.
//   kG0: l0 rois from t0, coalesced 1KB wave-loads (proven gather_roi).
// Fallback ws<82MB: exact R11 monolithic (69us proven).
// Predicted: kM 30-38us @4.5-5.5TB/s occ~50%; kG0 6-10us; total 38-48us.
// Rules: kM <4TB/s => occupancy still broken; total >= R11 => line-pipe
// floor is the roofline -> revert R11.

#define NUM_CH 256
#define CGRP   64
#define TBLK0  3200         // 2b * 200y * 4ctile * 2xhalf
#define WS_T0  20480000     // floats: 2*200*200*256

typedef float floatx2 __attribute__((ext_vector_type(2)));
typedef float floatx4 __attribute__((ext_vector_type(4)));

__device__ __forceinline__ float ext4(floatx4 v, int i) {
    float r = (i == 1) ? v.y : v.x;
    r = (i == 2) ? v.z : r;
    r = (i == 3) ? v.w : r;
    return r;
}

// ---- l0 transpose (C,H,W)->(H,W,C), x4 both sides (proven R17) ------------
__device__ __forceinline__ void transpose_l0(
    const float* __restrict__ src, float* __restrict__ dst, int m, float* lds)
{
    int b   = m / 1600;
    int rm  = m - b * 1600;
    int y   = rm >> 3;
    int sub = rm & 7;
    int ct  = sub >> 1;
    int xh  = sub & 1;
    int tid = threadIdx.x;
    const float* s = src + (((size_t)b * NUM_CH + ct * 64) * 200 + y) * 200
                         + xh * 100;
    for (int i = tid; i < 64 * 25; i += 256) {      // 64 ch x 25 dwordx4
        int c  = i / 25;
        int xq = i - c * 25;
        floatx4 v = *(const floatx4*)(s + (size_t)c * 40000 + xq * 4);
        float* L = lds + c * 101 + xq * 4;
        L[0] = v.x; L[1] = v.y; L[2] = v.z; L[3] = v.w;
    }
    __syncthreads();
    float* d = dst + (((size_t)b * 200 + y) * 200 + xh * 100) * (size_t)NUM_CH
                   + ct * 64;
    for (int i = tid; i < 100 * 16; i += 256) {     // 100 px x 16 dwordx4
        int x  = i >> 4;
        int cq = (i & 15) * 4;
        floatx4 v;
        v.x = lds[(cq + 0) * 101 + x];
        v.y = lds[(cq + 1) * 101 + x];
        v.z = lds[(cq + 2) * 101 + x];
        v.w = lds[(cq + 3) * 101 + x];
        *(floatx4*)(d + (size_t)x * NUM_CH + cq) = v;
    }
}

// ==== kM: l0 transpose (first) || R11 divergent gather (l1-3, no LDS) ======
__global__ __launch_bounds__(256) void k_main(
    const float* __restrict__ f0,
    const float* __restrict__ f1,
    const float* __restrict__ f2,
    const float* __restrict__ f3,
    const float* __restrict__ rois_f,
    const int* __restrict__ level,
    float* __restrict__ out,
    float* __restrict__ ws,
    int K, int tblk, int all_levels)
{
    __shared__ float lds[64 * 101];                 // 25.9KB -> 6 blocks/CU
    int bid = blockIdx.x;
    if (bid < tblk) {
        transpose_l0(f0, ws, bid, lds);
        return;
    }

    // ---- R11 divergent-gather body (proven), level-gated ------------------
    int lb  = bid - tblk;                           // tblk%8==0 -> XCD=lb&7
    int nb  = gridDim.x - tblk;                     // K*16
    int q   = nb >> 3, r = nb & 7;
    int xcd = lb & 7;
    int idx = lb >> 3;
    int l   = xcd * q + min(xcd, r) + idx;          // chunked XCD swizzle

    int NW  = K * CGRP;
    int wid = l * 4 + (int)(threadIdx.x >> 6);
    if (wid >= NW) return;
    int lane = threadIdx.x & 63;
    if (lane >= 49) return;

    int k  = wid % K;                               // roi   (inner)
    int c2 = wid / K;                               // cgrp  (outer)
    k  = __builtin_amdgcn_readfirstlane(k);
    c2 = __builtin_amdgcn_readfirstlane(c2);

    int lvl = level[k];
    if (!all_levels && lvl == 0) return;            // kG0 owns level 0

    const float* f;
    int H, W; float scale;
    if (lvl == 0)      { f = f0; H = 200; W = 200; scale = 0.25f;    }
    else if (lvl == 1) { f = f1; H = 100; W = 100; scale = 0.125f;   }
    else if (lvl == 2) { f = f2; H = 50;  W = 50;  scale = 0.0625f;  }
    else               { f = f3; H = 25;  W = 25;  scale = 0.03125f; }

    int p  = lane;
    int ph = p / 7;
    int pw = p % 7;

    const float* rf = rois_f + (size_t)k * 5;
    float r0 = rf[0];
    float x1 = rf[1] * scale, y1 = rf[2] * scale;
    float x2 = rf[3] * scale, y2 = rf[4] * scale;
    int bi = (int)r0;
    bi = (bi < 0) ? 0 : ((bi > 1) ? 1 : bi);

    float bh = fmaxf(y2 - y1, 1.0f) * (1.0f / 7.0f);
    float bw = fmaxf(x2 - x1, 1.0f) * (1.0f / 7.0f);

    const size_t plane = (size_t)(H * W);
    const float* base  = f + ((size_t)bi * NUM_CH + c2) * plane;
    const size_t cstr  = (size_t)CGRP * plane;

    int   rA[2], rB[2];
    float lyv[2], hyv[2], vy[2];
    #pragma unroll
    for (int sy = 0; sy < 2; ++sy) {
        float y = y1 + (float)ph * bh + ((float)sy + 0.5f) * (bh * 0.5f);
        bool valid = (y > -1.0f) && (y < (float)H);
        float yc = fmaxf(y, 0.0f);
        int yl = min((int)yc, H - 1);
        int yh = min(yl + 1, H - 1);
        float ly = (yl >= H - 1) ? 0.0f : (yc - (float)yl);
        rA[sy] = yl * W;
        rB[sy] = yh * W;
        lyv[sy] = ly; hyv[sy] = 1.0f - ly;
        vy[sy] = valid ? 0.25f : 0.0f;
    }
    int   xlv[2], xhv[2];
    float lxv[2], hxv[2], vx[2];
    #pragma unroll
    for (int sx = 0; sx < 2; ++sx) {
        float x = x1 + (float)pw * bw + ((float)sx + 0.5f) * (bw * 0.5f);
        bool valid = (x > -1.0f) && (x < (float)W);
        float xc = fmaxf(x, 0.0f);
        int xl = min((int)xc, W - 1);
        float lx = (xl >= W - 1) ? 0.0f : (xc - (float)xl);
        xlv[sx] = xl;
        xhv[sx] = min(xl + 1, W - 1);
        lxv[sx] = lx; hxv[sx] = 1.0f - lx;
        vx[sx] = valid ? 1.0f : 0.0f;
    }

    float acc[4];
    #pragma unroll
    for (int j = 0; j < 4; ++j) acc[j] = 0.0f;

    if (bw <= 3.98f) {
        int xq = min(xlv[0], W - 4);
        int i0l = min(max(xlv[0] - xq, 0), 3);
        int i0h = min(max(xhv[0] - xq, 0), 3);
        int i1l = min(max(xlv[1] - xq, 0), 3);
        int i1h = min(max(xhv[1] - xq, 0), 3);

        #pragma unroll
        for (int sy = 0; sy < 2; ++sy) {
            floatx4 LA[4], LB[4];
            #pragma unroll
            for (int j = 0; j < 4; ++j) {
                const float* bj = base + (size_t)j * cstr;
                LA[j] = *(const floatx4*)(bj + rA[sy] + xq);
                LB[j] = *(const floatx4*)(bj + rB[sy] + xq);
            }
            #pragma unroll
            for (int sx = 0; sx < 2; ++sx) {
                int il = sx ? i1l : i0l;
                int ih = sx ? i1h : i0h;
                float vs  = vy[sy] * vx[sx];
                float w00 = hyv[sy] * hxv[sx] * vs;
                float w01 = hyv[sy] * lxv[sx] * vs;
                float w10 = lyv[sy] * hxv[sx] * vs;
                float w11 = lyv[sy] * lxv[sx] * vs;
                #pragma unroll
                for (int j = 0; j < 4; ++j) {
                    acc[j] += w00 * ext4(LA[j], il) + w01 * ext4(LA[j], ih)
                            + w10 * ext4(LB[j], il) + w11 * ext4(LB[j], ih);
                }
            }
        }
    } else {
        int   xb[2];
        float sel[2];
        #pragma unroll
        for (int sx = 0; sx < 2; ++sx) {
            int xq = min(xlv[sx], W - 2);
            xb[sx]  = xq;
            sel[sx] = (xlv[sx] > xq) ? 1.0f : 0.0f;
        }
        #pragma unroll
        for (int sy = 0; sy < 2; ++sy) {
            floatx2 va[4][2], vb[4][2];
            #pragma unroll
            for (int sx = 0; sx < 2; ++sx) {
                #pragma unroll
                for (int j = 0; j < 4; ++j) {
                    const float* bj = base + (size_t)j * cstr;
                    va[j][sx] = *(const floatx2*)(bj + rA[sy] + xb[sx]);
                    vb[j][sx] = *(const floatx2*)(bj + rB[sy] + xb[sx]);
                }
            }
            #pragma unroll
            for (int sx = 0; sx < 2; ++sx) {
                float vs  = vy[sy] * vx[sx];
                float w00 = hyv[sy] * hxv[sx] * vs;
                float w01 = hyv[sy] * lxv[sx] * vs;
                float w10 = lyv[sy] * hxv[sx] * vs;
                float w11 = lyv[sy] * lxv[sx] * vs;
                float s0  = sel[sx];
                #pragma unroll
                for (int j = 0; j < 4; ++j) {
                    float v00 = va[j][sx].x + s0 * (va[j][sx].y - va[j][sx].x);
                    float v10 = vb[j][sx].x + s0 * (vb[j][sx].y - vb[j][sx].x);
                    acc[j] += w00 * v00 + w01 * va[j][sx].y
                            + w10 * v10 + w11 * vb[j][sx].y;
                }
            }
        }
    }

    size_t ob = ((size_t)k * NUM_CH + c2) * 49 + p;
    #pragma unroll
    for (int j = 0; j < 4; ++j)
        out[ob + (size_t)j * (CGRP * 49)] = acc[j];
}

// ==== kG0: coalesced channel-last gather of l0 rois (proven R15/R17) =======
__global__ __launch_bounds__(256) void k_g0(
    const float* __restrict__ rois_f,
    const int* __restrict__ level,
    const float* __restrict__ ws,
    float* __restrict__ out,
    int K)
{
    __shared__ float lds[49 * 257];                 // 50.4KB
    int k = blockIdx.x;
    if (level[k] != 0) return;

    const int H = 200, W = 200;
    const float scale = 0.25f;

    const float* rf = rois_f + (size_t)k * 5;
    float r0 = rf[0];
    float x1 = rf[1] * scale, y1 = rf[2] * scale;
    float x2 = rf[3] * scale, y2 = rf[4] * scale;
    int bi = (int)r0;
    bi = (bi < 0) ? 0 : ((bi > 1) ? 1 : bi);

    float bh = fmaxf(y2 - y1, 1.0f) * (1.0f / 7.0f);
    float bw = fmaxf(x2 - x1, 1.0f) * (1.0f / 7.0f);

    const float* tb = ws + (size_t)bi * H * W * NUM_CH;
    int wave = threadIdx.x >> 6;
    int lane = threadIdx.x & 63;
    int cb   = lane * 4;

    for (int px = wave; px < 49; px += 4) {
        int ph = px / 7, pw = px % 7;

        int rows[4]; float lyv[2], hyv[2], vy[2];
        #pragma unroll
        for (int sy = 0; sy < 2; ++sy) {
            float y = y1 + (float)ph * bh + ((float)sy + 0.5f) * (bh * 0.5f);
            bool valid = (y > -1.0f) && (y < (float)H);
            float yc = fmaxf(y, 0.0f);
            int yl = min((int)yc, H - 1);
            int yh = min(yl + 1, H - 1);
            float ly = (yl >= H - 1) ? 0.0f : (yc - (float)yl);
            rows[2 * sy]     = yl;
            rows[2 * sy + 1] = yh;
            lyv[sy] = ly; hyv[sy] = 1.0f - ly;
            vy[sy] = valid ? 0.25f : 0.0f;
        }
        int cols[4]; float lxv[2], hxv[2], vx[2];
        #pragma unroll
        for (int sx = 0; sx < 2; ++sx) {
            float x = x1 + (float)pw * bw + ((float)sx + 0.5f) * (bw * 0.5f);
            bool valid = (x > -1.0f) && (x < (float)W);
            float xc = fmaxf(x, 0.0f);
            int xl = min((int)xc, W - 1);
            float lx = (xl >= W - 1) ? 0.0f : (xc - (float)xl);
            cols[2 * sx]     = xl;
            cols[2 * sx + 1] = min(xl + 1, W - 1);
            lxv[sx] = lx; hxv[sx] = 1.0f - lx;
            vx[sx] = valid ? 1.0f : 0.0f;
        }

        floatx4 v[4][4];
        #pragma unroll
        for (int rr = 0; rr < 4; ++rr) {
            #pragma unroll
            for (int cc = 0; cc < 4; ++cc) {
                v[rr][cc] = *(const floatx4*)(
                    tb + ((size_t)rows[rr] * W + cols[cc]) * NUM_CH + cb);
            }
        }

        floatx4 acc = {0.0f, 0.0f, 0.0f, 0.0f};
        #pragma unroll
        for (int sy = 0; sy < 2; ++sy) {
            #pragma unroll
            for (int sx = 0; sx < 2; ++sx) {
                float vs  = vy[sy] * vx[sx];
                float w00 = hyv[sy] * hxv[sx] * vs;
                float w01 = hyv[sy] * lxv[sx] * vs;
                float w10 = lyv[sy] * hxv[sx] * vs;
                float w11 = lyv[sy] * lxv[sx] * vs;
                acc += v[2 * sy][2 * sx]         * w00;
                acc += v[2 * sy][2 * sx + 1]     * w01;
                acc += v[2 * sy + 1][2 * sx]     * w10;
                acc += v[2 * sy + 1][2 * sx + 1] * w11;
            }
        }

        int lb = px * 257 + cb;
        lds[lb + 0] = acc.x;
        lds[lb + 1] = acc.y;
        lds[lb + 2] = acc.z;
        lds[lb + 3] = acc.w;
    }
    __syncthreads();

    float* ob = out + (size_t)k * (NUM_CH * 49);
    for (int i = threadIdx.x; i < NUM_CH * 49; i += 256) {
        int c  = i / 49;
        int px = i - c * 49;
        ob[i] = lds[px * 257 + c];
    }
}

extern "C" void kernel_launch(void* const* d_in, const int* in_sizes, int n_in,
                              void* d_out, int out_size, void* d_ws, size_t ws_size,
                              hipStream_t stream) {
    const float* f0   = (const float*)d_in[0];
    const float* f1   = (const float*)d_in[1];
    const float* f2   = (const float*)d_in[2];
    const float* f3   = (const float*)d_in[3];
    const float* rois = (const float*)d_in[4];
    // d_in[5] = rois_counts (unused)
    const int* level = (const int*)d_in[6];
    float* out = (float*)d_out;
    float* ws  = (float*)d_ws;

    int K  = out_size / (NUM_CH * 49);
    int GB = K * 16;                         // K*64 gather waves

    if (ws_size >= (size_t)WS_T0 * 4) {
        k_main<<<TBLK0 + GB, 256, 0, stream>>>(
            f0, f1, f2, f3, rois, level, out, ws, K, TBLK0, 0);
        k_g0<<<K, 256, 0, stream>>>(rois, level, ws, out, K);
    } else {
        // fallback: exact R11 monolithic divergent gather (proven 69us)
        k_main<<<GB, 256, 0, stream>>>(
            f0, f1, f2, f3, rois, level, out, ws, K, 0, 1);
    }
}

// Round 10
// 184.082 us; speedup vs baseline: 1.2074x; 1.1333x over previous
//
#include <hip/hip_runtime.h>

// ROI Align (FPN, PH=PW=7, SR=2), fp32 I/O.
// R19 = REVERT to R11 (session argmin: 69.3us/dispatch, harness 184.98us).
// Nine-round record: R11's channel-outer/roi-inner divergent gather with
// chunked XCD swizzle beats every tested alternative:
//   R12 packing/row-dedup 73.8 | R14 LDS staging 129.8 | R15/R17/R18
//   channel-last transpose hybrids 77-88us (transpose never exceeds
//   2.6TB/s fused; L2 thrash breaks the gather; g13+g0 line-events ~27us).
// Calibrated model: time ~= line-touch events x ~4.4cy/CU divergent /
// ~2.6cy contiguous on the per-CU vector-memory line-service pipe. R11 ~=
// 5.5M+ line-events ~= 69us. HBM 15%, VALU 30%, occ 32% are all slack;
// the line pipe is the binding (and counter-invisible) resource.
// FETCH 49MB ~= compulsory (L2-sliced by the swizzle); WRITE 32.4MB
// (49/64-lane store amp; fixing it via packing cost more than it saved).

#define NUM_CH 256
#define CPT    4            // channels per thread
#define CGRP   64           // NUM_CH / CPT

typedef float floatx2 __attribute__((ext_vector_type(2)));
typedef float floatx4 __attribute__((ext_vector_type(4)));

__device__ __forceinline__ float ext4(floatx4 v, int i) {
    float r = (i == 1) ? v.y : v.x;
    r = (i == 2) ? v.z : r;
    r = (i == 3) ? v.w : r;
    return r;
}

__global__ __launch_bounds__(256) void roi_align_kernel(
    const float* __restrict__ f0,
    const float* __restrict__ f1,
    const float* __restrict__ f2,
    const float* __restrict__ f3,
    const float* __restrict__ rois_f,
    const int* __restrict__ level,
    float* __restrict__ out,
    int K,                           // number of rois
    int NW)                          // total waves = K * CGRP
{
    // ---- chunked XCD swizzle: physical block b -> logical block l ---------
    // HW round-robins blocks across 8 XCDs (b % 8). Give XCD x a CONTIGUOUS
    // logical range so its L2 sees a small, stable channel slice.
    int nb  = gridDim.x;
    int q   = nb >> 3, r = nb & 7;
    int xcd = blockIdx.x & 7;
    int idx = blockIdx.x >> 3;
    int l   = xcd * q + min(xcd, r) + idx;          // bijective for any nb

    int wid = l * 4 + (int)(threadIdx.x >> 6);      // logical wave id
    if (wid >= NW) return;
    int lane = threadIdx.x & 63;
    if (lane >= 49) return;                         // 49 px per wave

    int k  = wid % K;                               // roi   (inner)
    int c2 = wid / K;                               // cgrp  (outer)
    k  = __builtin_amdgcn_readfirstlane(k);         // wave-uniform -> SGPR
    c2 = __builtin_amdgcn_readfirstlane(c2);

    int p  = lane;
    int ph = p / 7;
    int pw = p % 7;

    int lvl = level[k];
    const float* f;
    int H, W; float scale;
    if (lvl == 0)      { f = f0; H = 200; W = 200; scale = 0.25f;    }
    else if (lvl == 1) { f = f1; H = 100; W = 100; scale = 0.125f;   }
    else if (lvl == 2) { f = f2; H = 50;  W = 50;  scale = 0.0625f;  }
    else               { f = f3; H = 25;  W = 25;  scale = 0.03125f; }

    const float* rf = rois_f + (size_t)k * 5;
    float r0 = rf[0];
    float x1 = rf[1] * scale, y1 = rf[2] * scale;
    float x2 = rf[3] * scale, y2 = rf[4] * scale;
    int bi = (int)r0;
    bi = (bi < 0) ? 0 : ((bi > 1) ? 1 : bi);

    float bh = fmaxf(y2 - y1, 1.0f) * (1.0f / 7.0f);
    float bw = fmaxf(x2 - x1, 1.0f) * (1.0f / 7.0f);

    const size_t plane = (size_t)(H * W);
    const float* base  = f + ((size_t)bi * NUM_CH + c2) * plane;
    const size_t cstr  = (size_t)CGRP * plane;   // stride between my channels

    // ---- factored geometry: 2 y-samples + 2 x-samples (channel-invariant) -
    int   rA[2], rB[2];
    float lyv[2], hyv[2], vy[2];
    #pragma unroll
    for (int sy = 0; sy < 2; ++sy) {
        float y = y1 + (float)ph * bh + ((float)sy + 0.5f) * (bh * 0.5f);
        bool valid = (y > -1.0f) && (y < (float)H);
        float yc = fmaxf(y, 0.0f);
        int yl = min((int)yc, H - 1);
        int yh = min(yl + 1, H - 1);
        float ly = (yl >= H - 1) ? 0.0f : (yc - (float)yl);
        rA[sy] = yl * W;
        rB[sy] = yh * W;
        lyv[sy] = ly; hyv[sy] = 1.0f - ly;
        vy[sy] = valid ? 0.25f : 0.0f;     // fold 2x2 mean into y validity
    }
    int   xlv[2], xhv[2];
    float lxv[2], hxv[2], vx[2];
    #pragma unroll
    for (int sx = 0; sx < 2; ++sx) {
        float x = x1 + (float)pw * bw + ((float)sx + 0.5f) * (bw * 0.5f);
        bool valid = (x > -1.0f) && (x < (float)W);
        float xc = fmaxf(x, 0.0f);
        int xl = min((int)xc, W - 1);
        float lx = (xl >= W - 1) ? 0.0f : (xc - (float)xl);
        xlv[sx] = xl;
        xhv[sx] = min(xl + 1, W - 1);
        lxv[sx] = lx; hxv[sx] = 1.0f - lx;
        vx[sx] = valid ? 1.0f : 0.0f;
    }

    float acc[CPT];
    #pragma unroll
    for (int j = 0; j < CPT; ++j) acc[j] = 0.0f;

    if (bw <= 3.98f) {
        // ---- merged path: x-span of all 4 x-corners fits a 4-float window -
        int xq = min(xlv[0], W - 4);               // window base (>=0: W>=25)
        int i0l = min(max(xlv[0] - xq, 0), 3);
        int i0h = min(max(xhv[0] - xq, 0), 3);
        int i1l = min(max(xlv[1] - xq, 0), 3);
        int i1h = min(max(xhv[1] - xq, 0), 3);

        #pragma unroll
        for (int sy = 0; sy < 2; ++sy) {
            floatx4 LA[CPT], LB[CPT];
            #pragma unroll
            for (int j = 0; j < CPT; ++j) {
                const float* bj = base + (size_t)j * cstr;
                LA[j] = *(const floatx4*)(bj + rA[sy] + xq);  // row yl
                LB[j] = *(const floatx4*)(bj + rB[sy] + xq);  // row yh
            }
            #pragma unroll
            for (int sx = 0; sx < 2; ++sx) {
                int il = sx ? i1l : i0l;
                int ih = sx ? i1h : i0h;
                float vs  = vy[sy] * vx[sx];
                float w00 = hyv[sy] * hxv[sx] * vs;
                float w01 = hyv[sy] * lxv[sx] * vs;
                float w10 = lyv[sy] * hxv[sx] * vs;
                float w11 = lyv[sy] * lxv[sx] * vs;
                #pragma unroll
                for (int j = 0; j < CPT; ++j) {
                    acc[j] += w00 * ext4(LA[j], il) + w01 * ext4(LA[j], ih)
                            + w10 * ext4(LB[j], il) + w11 * ext4(LB[j], ih);
                }
            }
        }
    } else {
        // ---- wide-ROI path: 8 dwordx2 gathers per channel ----------------
        int   xb[2];
        float sel[2];
        #pragma unroll
        for (int sx = 0; sx < 2; ++sx) {
            int xq = min(xlv[sx], W - 2);
            xb[sx]  = xq;
            sel[sx] = (xlv[sx] > xq) ? 1.0f : 0.0f;
        }
        #pragma unroll
        for (int sy = 0; sy < 2; ++sy) {
            floatx2 va[CPT][2], vb[CPT][2];
            #pragma unroll
            for (int sx = 0; sx < 2; ++sx) {
                #pragma unroll
                for (int j = 0; j < CPT; ++j) {
                    const float* bj = base + (size_t)j * cstr;
                    va[j][sx] = *(const floatx2*)(bj + rA[sy] + xb[sx]);
                    vb[j][sx] = *(const floatx2*)(bj + rB[sy] + xb[sx]);
                }
            }
            #pragma unroll
            for (int sx = 0; sx < 2; ++sx) {
                float vs  = vy[sy] * vx[sx];
                float w00 = hyv[sy] * hxv[sx] * vs;
                float w01 = hyv[sy] * lxv[sx] * vs;
                float w10 = lyv[sy] * hxv[sx] * vs;
                float w11 = lyv[sy] * lxv[sx] * vs;
                float s0  = sel[sx];
                #pragma unroll
                for (int j = 0; j < CPT; ++j) {
                    float v00 = va[j][sx].x + s0 * (va[j][sx].y - va[j][sx].x);
                    float v10 = vb[j][sx].x + s0 * (vb[j][sx].y - vb[j][sx].x);
                    acc[j] += w00 * v00 + w01 * va[j][sx].y
                            + w10 * v10 + w11 * vb[j][sx].y;
                }
            }
        }
    }

    size_t ob = ((size_t)k * NUM_CH + c2) * 49 + p;
    #pragma unroll
    for (int j = 0; j < CPT; ++j)
        out[ob + (size_t)j * (CGRP * 49)] = acc[j];
}

extern "C" void kernel_launch(void* const* d_in, const int* in_sizes, int n_in,
                              void* d_out, int out_size, void* d_ws, size_t ws_size,
                              hipStream_t stream) {
    const float* f0   = (const float*)d_in[0];
    const float* f1   = (const float*)d_in[1];
    const float* f2   = (const float*)d_in[2];
    const float* f3   = (const float*)d_in[3];
    const float* rois = (const float*)d_in[4];
    // d_in[5] = rois_counts (unused)
    const int* level = (const int*)d_in[6];
    float* out = (float*)d_out;

    int K  = out_size / (NUM_CH * 49);   // rois
    int NW = K * CGRP;                   // one wave per (channel-group, roi)
    int threads = 256;                   // 4 waves per block
    int blocks  = (NW + 3) / 4;
    roi_align_kernel<<<blocks, threads, 0, stream>>>(f0, f1, f2, f3, rois, level, out, K, NW);
}